// Round 4
// baseline (367.538 us; speedup 1.0000x reference)
//
#include <hip/hip_runtime.h>
#include <math.h>

#define NEG 0.2f
typedef unsigned short u16;
typedef __bf16 bf16x8 __attribute__((ext_vector_type(8)));
typedef float f32x4 __attribute__((ext_vector_type(4)));

__device__ __forceinline__ float bf2f(u16 u) {
    union { unsigned i; float f; } x; x.i = ((unsigned)u) << 16; return x.f;
}
__device__ __forceinline__ u16 f2bf(float f) {
    union { float f; unsigned u; } x; x.f = f;
    unsigned r = x.u + 0x7fffu + ((x.u >> 16) & 1u);
    return (u16)(r >> 16);
}

// ---------------- utility ----------------
__global__ void zero_i32(int* __restrict__ p, int n) {
    int i = blockIdx.x * blockDim.x + threadIdx.x;
    if (i < n) p[i] = 0;
}

__global__ void hist_kernel(const int* __restrict__ ei, int E, int N, int* __restrict__ cnt) {
    int i = blockIdx.x * blockDim.x + threadIdx.x;
    int tot = E + N;
    if (i >= tot) return;
    int d = (i < E) ? ei[E + i] : (i - E);
    atomicAdd(&cnt[d], 1);
}

__global__ void bsum_kernel(const int* __restrict__ cnt, int* __restrict__ bsum, int N) {
    __shared__ int sd[256];
    int i = blockIdx.x * 256 + threadIdx.x;
    sd[threadIdx.x] = (i < N) ? cnt[i] : 0;
    __syncthreads();
    for (int off = 128; off; off >>= 1) {
        if (threadIdx.x < off) sd[threadIdx.x] += sd[threadIdx.x + off];
        __syncthreads();
    }
    if (threadIdx.x == 0) bsum[blockIdx.x] = sd[0];
}

__global__ void bscan_kernel(const int* __restrict__ bsum, int* __restrict__ bbase, int NB) {
    __shared__ int sd[256];
    int t = threadIdx.x;
    int v = (t < NB) ? bsum[t] : 0;
    sd[t] = v;
    __syncthreads();
    for (int off = 1; off < 256; off <<= 1) {
        int u = (t >= off) ? sd[t - off] : 0;
        __syncthreads();
        sd[t] += u;
        __syncthreads();
    }
    if (t < NB) bbase[t] = sd[t] - v;
}

__global__ void local_scan_kernel(const int* __restrict__ cnt, const int* __restrict__ bbase,
                                  int* __restrict__ row_ptr, int* __restrict__ cursor,
                                  int N, int ET) {
    __shared__ int sd[256];
    int t = threadIdx.x;
    int i = blockIdx.x * 256 + t;
    int v = (i < N) ? cnt[i] : 0;
    sd[t] = v;
    __syncthreads();
    for (int off = 1; off < 256; off <<= 1) {
        int u = (t >= off) ? sd[t - off] : 0;
        __syncthreads();
        sd[t] += u;
        __syncthreads();
    }
    if (i < N) {
        int e = bbase[blockIdx.x] + sd[t] - v;
        row_ptr[i] = e;
        cursor[i] = e;
    }
    if (i == 0) row_ptr[N] = ET;
}

__global__ void scatter_kernel(const int* __restrict__ ei, int E, int N,
                               int* __restrict__ cursor, int* __restrict__ col) {
    int i = blockIdx.x * blockDim.x + threadIdx.x;
    int tot = E + N;
    if (i >= tot) return;
    int s, d;
    if (i < E) { s = ei[i]; d = ei[E + i]; }
    else       { s = i - E; d = s; }
    int pos = atomicAdd(&cursor[d], 1);
    col[pos] = s;
}

// ---------------- prep: W1T bf16 (272 rows: 256 cols of W1T + 8 att-folded + 8 zero) ---
// w1x[c][k] = W1[k][c] for c<256; rows 256..259 = A1_src heads, 260..263 = A1_dst heads,
// 264..271 = zero.  A1_src[k][h] = sum_c W1[k][h*64+c]*att_s[h][c].
__global__ void prep_w1(const float* __restrict__ W1, const float* __restrict__ att_s,
                        const float* __restrict__ att_d, u16* __restrict__ w1x) {
    int k = blockIdx.x;        // 0..255
    int c = threadIdx.x;       // 0..255
    float w = W1[k * 256 + c];
    w1x[c * 256 + k] = f2bf(w);
    int head = c >> 6;         // wave index
    float vs = w * att_s[c];
    float vd = w * att_d[c];
#pragma unroll
    for (int mask = 1; mask < 64; mask <<= 1) {
        vs += __shfl_xor(vs, mask, 64);
        vd += __shfl_xor(vd, mask, 64);
    }
    if ((c & 63) == 0) {
        w1x[(256 + head) * 256 + k] = f2bf(vs);
        w1x[(260 + head) * 256 + k] = f2bf(vd);
        w1x[(264 + head) * 256 + k] = 0;
        w1x[(268 + head) * 256 + k] = 0;
    }
}

// ---------------- GEMM1 direct MFMA: no LDS, no barriers ----------------
// one wave = 16 rows x 272 cols; acc[17] f32x4; A from fp32 x (in-reg cvt), B from w1x.
__global__ __launch_bounds__(256) void gemm1_direct(const float* __restrict__ x,
                                                    const u16* __restrict__ w1x,
                                                    u16* __restrict__ h1b,
                                                    float* __restrict__ asad, int N) {
    int wid = (blockIdx.x * 256 + threadIdx.x) >> 6;
    int lane = threadIdx.x & 63;
    int r0 = wid << 4;
    if (r0 >= N) return;
    int g = lane >> 4, l15 = lane & 15;
    int arow = r0 + l15; if (arow > N - 1) arow = N - 1;
    const float* xp = x + (size_t)arow * 256 + g * 8;
    const u16* wp = w1x + (size_t)l15 * 256 + g * 8;

    f32x4 acc[17];
#pragma unroll
    for (int n = 0; n < 17; ++n) acc[n] = (f32x4){0.f, 0.f, 0.f, 0.f};

#pragma unroll
    for (int ks = 0; ks < 8; ++ks) {
        float4 a0 = *reinterpret_cast<const float4*>(xp + ks * 32);
        float4 a1 = *reinterpret_cast<const float4*>(xp + ks * 32 + 4);
        bf16x8 af;
        af[0] = (__bf16)a0.x; af[1] = (__bf16)a0.y; af[2] = (__bf16)a0.z; af[3] = (__bf16)a0.w;
        af[4] = (__bf16)a1.x; af[5] = (__bf16)a1.y; af[6] = (__bf16)a1.z; af[7] = (__bf16)a1.w;
#pragma unroll
        for (int n = 0; n < 17; ++n) {
            bf16x8 bf = *reinterpret_cast<const bf16x8*>(wp + (size_t)n * 16 * 256 + ks * 32);
            acc[n] = __builtin_amdgcn_mfma_f32_16x16x32_bf16(af, bf, acc[n], 0, 0, 0);
        }
    }

    // epilogue: C/D layout col=lane&15, row=(lane>>4)*4+reg
#pragma unroll
    for (int reg = 0; reg < 4; ++reg) {
        int row = r0 + g * 4 + reg;
        if (row < N) {
#pragma unroll
            for (int n = 0; n < 16; ++n)
                h1b[(size_t)row * 256 + n * 16 + l15] = f2bf(acc[n][reg]);
            if (l15 < 8) asad[(size_t)row * 8 + l15] = acc[16][reg];
        }
    }
}

// ---------------- conv1 softmax: single sweep, reg-cached e (deg<=128 fast path) -----
__global__ void att_alpha1(const float* __restrict__ asad, const int* __restrict__ row_ptr,
                           const int* __restrict__ col, float* __restrict__ alphas,
                           float* __restrict__ invl, int N, int ETpad) {
    int idx = blockIdx.x * blockDim.x + threadIdx.x;
    int v = idx >> 6, lane = idx & 63;
    if (v >= N) return;
    int head = lane >> 4, l15 = lane & 15;
    float adst = asad[(size_t)v * 8 + 4 + head];
    int beg = row_ptr[v], end = row_ptr[v + 1];
    float* ap = alphas + (size_t)head * ETpad;
    int p0 = beg + l15;
    if (end - beg <= 128) {
        float e[8];
#pragma unroll
        for (int i = 0; i < 8; ++i) {
            int p = p0 + i * 16;
            float ev = -1e30f;
            if (p < end) {
                int u = col[p];
                float tv = asad[(size_t)u * 8 + head] + adst;
                ev = tv > 0.f ? tv : NEG * tv;
            }
            e[i] = ev;
        }
        float m = e[0];
#pragma unroll
        for (int i = 1; i < 8; ++i) m = fmaxf(m, e[i]);
#pragma unroll
        for (int mask = 1; mask < 16; mask <<= 1) m = fmaxf(m, __shfl_xor(m, mask, 64));
        float l = 0.f;
#pragma unroll
        for (int i = 0; i < 8; ++i) {
            int p = p0 + i * 16;
            if (p < end) { float a = __expf(e[i] - m); ap[p] = a; l += a; }
        }
#pragma unroll
        for (int mask = 1; mask < 16; mask <<= 1) l += __shfl_xor(l, mask, 64);
        if (l15 == 0) invl[v * 4 + head] = 1.f / (l + 1e-16f);
    } else {
        float m = -1e30f;
        for (int p = p0; p < end; p += 16) {
            int u = col[p];
            float tv = asad[(size_t)u * 8 + head] + adst;
            tv = tv > 0.f ? tv : NEG * tv;
            ap[p] = tv;
            m = fmaxf(m, tv);
        }
#pragma unroll
        for (int mask = 1; mask < 16; mask <<= 1) m = fmaxf(m, __shfl_xor(m, mask, 64));
        float l = 0.f;
        for (int p = p0; p < end; p += 16) { float a = __expf(ap[p] - m); ap[p] = a; l += a; }
#pragma unroll
        for (int mask = 1; mask < 16; mask <<= 1) l += __shfl_xor(l, mask, 64);
        if (l15 == 0) invl[v * 4 + head] = 1.f / (l + 1e-16f);
    }
}

// ---------------- conv1 gather ----------------
__global__ void conv1_gather(const u16* __restrict__ h1b, const float* __restrict__ alphas,
                             const float* __restrict__ invl, const int* __restrict__ row_ptr,
                             const int* __restrict__ col, const float* __restrict__ b1,
                             u16* __restrict__ hin2b, int N, int ETpad) {
    int idx = blockIdx.x * blockDim.x + threadIdx.x;
    int v = idx >> 6, lane = idx & 63;
    if (v >= N) return;
    int head = lane >> 4;
    const float* ap = alphas + (size_t)head * ETpad;
    int beg = row_ptr[v], end = row_ptr[v + 1];
    float ax = 0.f, ay = 0.f, az = 0.f, aw = 0.f;
    int p = beg;
    for (; p + 3 < end; p += 4) {
        int u0 = col[p], u1 = col[p + 1], u2 = col[p + 2], u3 = col[p + 3];
        float a0 = ap[p], a1 = ap[p + 1], a2 = ap[p + 2], a3 = ap[p + 3];
        ushort4 h0 = *reinterpret_cast<const ushort4*>(h1b + (size_t)u0 * 256 + lane * 4);
        ushort4 h1 = *reinterpret_cast<const ushort4*>(h1b + (size_t)u1 * 256 + lane * 4);
        ushort4 h2 = *reinterpret_cast<const ushort4*>(h1b + (size_t)u2 * 256 + lane * 4);
        ushort4 h3 = *reinterpret_cast<const ushort4*>(h1b + (size_t)u3 * 256 + lane * 4);
        ax += a0 * bf2f(h0.x) + a1 * bf2f(h1.x) + a2 * bf2f(h2.x) + a3 * bf2f(h3.x);
        ay += a0 * bf2f(h0.y) + a1 * bf2f(h1.y) + a2 * bf2f(h2.y) + a3 * bf2f(h3.y);
        az += a0 * bf2f(h0.z) + a1 * bf2f(h1.z) + a2 * bf2f(h2.z) + a3 * bf2f(h3.z);
        aw += a0 * bf2f(h0.w) + a1 * bf2f(h1.w) + a2 * bf2f(h2.w) + a3 * bf2f(h3.w);
    }
    for (; p < end; ++p) {
        int u = col[p];
        float a = ap[p];
        ushort4 hv = *reinterpret_cast<const ushort4*>(h1b + (size_t)u * 256 + lane * 4);
        ax += a * bf2f(hv.x);
        ay += a * bf2f(hv.y);
        az += a * bf2f(hv.z);
        aw += a * bf2f(hv.w);
    }
    float inv = invl[v * 4 + head];
    int c = lane * 4;
    ushort4 o;
    o.x = f2bf(fmaxf(ax * inv + b1[c + 0], 0.f));
    o.y = f2bf(fmaxf(ay * inv + b1[c + 1], 0.f));
    o.z = f2bf(fmaxf(az * inv + b1[c + 2], 0.f));
    o.w = f2bf(fmaxf(aw * inv + b1[c + 3], 0.f));
    *reinterpret_cast<ushort4*>(hin2b + (size_t)v * 256 + c) = o;
}

// ---------------- GEMM2 (256->32), 64 nodes/block, k-step 8, fused att2 ----------
__global__ __launch_bounds__(256) void gemm2_att(const u16* __restrict__ hin2b,
                                                 const float* __restrict__ W2,
                                                 const float* __restrict__ att_s,
                                                 const float* __restrict__ att_d,
                                                 u16* __restrict__ h2b, float* __restrict__ as2,
                                                 float* __restrict__ ad2, int N) {
    __shared__ __align__(16) float ws2[256 * 32];
    int t = threadIdx.x;
#pragma unroll
    for (int i = 0; i < 8; ++i) {
        int f4 = i * 256 + t;
        *reinterpret_cast<float4*>(ws2 + f4 * 4) = *reinterpret_cast<const float4*>(W2 + f4 * 4);
    }
    __syncthreads();
    int half = t >> 5, j = t & 31;
    int nb = blockIdx.x * 64 + half * 8;
    float acc[8] = {};
    int nmax = N - 1;
    for (int k0 = 0; k0 < 256; k0 += 8) {
        float w[8];
#pragma unroll
        for (int i = 0; i < 8; ++i) w[i] = ws2[(k0 + i) * 32 + j];
#pragma unroll
        for (int q = 0; q < 8; ++q) {
            int nc = nb + q; nc = nc > nmax ? nmax : nc;
            uint4 hv = *reinterpret_cast<const uint4*>(hin2b + (size_t)nc * 256 + k0);
            acc[q] += bf2f((u16)(hv.x & 0xffff)) * w[0] + bf2f((u16)(hv.x >> 16)) * w[1]
                    + bf2f((u16)(hv.y & 0xffff)) * w[2] + bf2f((u16)(hv.y >> 16)) * w[3]
                    + bf2f((u16)(hv.z & 0xffff)) * w[4] + bf2f((u16)(hv.z >> 16)) * w[5]
                    + bf2f((u16)(hv.w & 0xffff)) * w[6] + bf2f((u16)(hv.w >> 16)) * w[7];
        }
    }
    float asj = att_s[j], adj = att_d[j];
#pragma unroll
    for (int q = 0; q < 8; ++q) {
        int n = nb + q;
        bool ok = n < N;
        float a = acc[q];
        if (ok) h2b[(size_t)n * 32 + j] = f2bf(a);
        float vs = a * asj, vd = a * adj;
#pragma unroll
        for (int mask = 1; mask < 32; mask <<= 1) {
            vs += __shfl_xor(vs, mask, 64);
            vd += __shfl_xor(vd, mask, 64);
        }
        if (j == 0 && ok) { as2[n] = vs; ad2[n] = vd; }
    }
}

// ---------------- conv2 softmax: single sweep, reg-cached ----------------
__global__ void att_alpha2(const float* __restrict__ as2, const float* __restrict__ ad2,
                           const int* __restrict__ row_ptr, const int* __restrict__ col,
                           float* __restrict__ alphas2, float* __restrict__ invl2, int N) {
    int idx = blockIdx.x * blockDim.x + threadIdx.x;
    int v = idx >> 6, lane = idx & 63;
    if (v >= N) return;
    float adst = ad2[v];
    int beg = row_ptr[v], end = row_ptr[v + 1];
    int p0 = beg + lane;
    if (end - beg <= 128) {
        float e0 = -1e30f, e1 = -1e30f;
        if (p0 < end) { float tv = as2[col[p0]] + adst; e0 = tv > 0.f ? tv : NEG * tv; }
        if (p0 + 64 < end) { float tv = as2[col[p0 + 64]] + adst; e1 = tv > 0.f ? tv : NEG * tv; }
        float m = fmaxf(e0, e1);
#pragma unroll
        for (int mask = 1; mask < 64; mask <<= 1) m = fmaxf(m, __shfl_xor(m, mask, 64));
        float l = 0.f;
        if (p0 < end) { float a = __expf(e0 - m); alphas2[p0] = a; l += a; }
        if (p0 + 64 < end) { float a = __expf(e1 - m); alphas2[p0 + 64] = a; l += a; }
#pragma unroll
        for (int mask = 1; mask < 64; mask <<= 1) l += __shfl_xor(l, mask, 64);
        if (lane == 0) invl2[v] = 1.f / (l + 1e-16f);
    } else {
        float m = -1e30f;
        for (int p = p0; p < end; p += 64) {
            float tv = as2[col[p]] + adst;
            tv = tv > 0.f ? tv : NEG * tv;
            alphas2[p] = tv;
            m = fmaxf(m, tv);
        }
#pragma unroll
        for (int mask = 1; mask < 64; mask <<= 1) m = fmaxf(m, __shfl_xor(m, mask, 64));
        float l = 0.f;
        for (int p = p0; p < end; p += 64) { float a = __expf(alphas2[p] - m); alphas2[p] = a; l += a; }
#pragma unroll
        for (int mask = 1; mask < 64; mask <<= 1) l += __shfl_xor(l, mask, 64);
        if (lane == 0) invl2[v] = 1.f / (l + 1e-16f);
    }
}

// ---------------- conv2 gather (32 lanes per node) ----------------
__global__ void conv2_gather(const u16* __restrict__ h2b, const float* __restrict__ alphas2,
                             const float* __restrict__ invl2, const int* __restrict__ row_ptr,
                             const int* __restrict__ col, const float* __restrict__ b2,
                             float* __restrict__ out2, int N) {
    int idx = blockIdx.x * blockDim.x + threadIdx.x;
    int v = idx >> 5, lane = idx & 31;
    if (v >= N) return;
    int beg = row_ptr[v], end = row_ptr[v + 1];
    float acc = 0.f;
    int p = beg;
    for (; p + 3 < end; p += 4) {
        int u0 = col[p], u1 = col[p + 1], u2 = col[p + 2], u3 = col[p + 3];
        float a0 = alphas2[p], a1 = alphas2[p + 1], a2 = alphas2[p + 2], a3 = alphas2[p + 3];
        float v0 = bf2f(h2b[(size_t)u0 * 32 + lane]);
        float v1 = bf2f(h2b[(size_t)u1 * 32 + lane]);
        float v2 = bf2f(h2b[(size_t)u2 * 32 + lane]);
        float v3 = bf2f(h2b[(size_t)u3 * 32 + lane]);
        acc += a0 * v0 + a1 * v1 + a2 * v2 + a3 * v3;
    }
    for (; p < end; ++p) {
        acc += alphas2[p] * bf2f(h2b[(size_t)col[p] * 32 + lane]);
    }
    out2[(size_t)v * 32 + lane] = acc * invl2[v] + b2[lane];
}

// ---------------- pooling + FC head ----------------
__global__ __launch_bounds__(256) void pool_fc(const float* __restrict__ out2,
                                               const int* __restrict__ batch,
                                               const float* __restrict__ fc1w,
                                               const float* __restrict__ fc1b,
                                               const float* __restrict__ fc2w,
                                               const float* __restrict__ fc2b,
                                               float* __restrict__ out, int N) {
    int g = blockIdx.x;
    int lo = 0, hi = N;
    while (lo < hi) { int mid = (lo + hi) >> 1; if (batch[mid] < g) lo = mid + 1; else hi = mid; }
    int s = lo;
    lo = 0; hi = N;
    while (lo < hi) { int mid = (lo + hi) >> 1; if (batch[mid] < g + 1) lo = mid + 1; else hi = mid; }
    int e = lo;

    int c = threadIdx.x & 31, grp = threadIdx.x >> 5;
    float sum = 0.f;
    for (int r = s + grp; r < e; r += 8) sum += out2[(size_t)r * 32 + c];
    __shared__ float part[8][32];
    part[grp][c] = sum;
    __syncthreads();
    __shared__ float g0[32];
    if (grp == 0) {
        float tot = 0.f;
#pragma unroll
        for (int q = 0; q < 8; ++q) tot += part[q][c];
        float cnt = (float)(e - s);
        g0[c] = fmaxf(tot / fmaxf(cnt, 1.0f), 0.f);
    }
    __syncthreads();
    __shared__ float z1[16];
    if (threadIdx.x < 16) {
        float a = fc1b[threadIdx.x];
        for (int k = 0; k < 32; ++k) a += g0[k] * fc1w[k * 16 + threadIdx.x];
        z1[threadIdx.x] = fmaxf(a, 0.f);
    }
    __syncthreads();
    if (threadIdx.x < 16) {
        float a = fc2b[threadIdx.x];
        for (int k = 0; k < 16; ++k) a += z1[k] * fc2w[k * 16 + threadIdx.x];
        out[g * 16 + threadIdx.x] = fmaxf(a, 0.f);
    }
}

// ---------------- host launcher ----------------
extern "C" void kernel_launch(void* const* d_in, const int* in_sizes, int n_in,
                              void* d_out, int out_size, void* d_ws, size_t ws_size,
                              hipStream_t stream) {
    const float* x      = (const float*)d_in[0];
    const int*   ei     = (const int*)d_in[1];
    const int*   batch  = (const int*)d_in[2];
    const float* W1     = (const float*)d_in[3];
    const float* att_s1 = (const float*)d_in[4];
    const float* att_d1 = (const float*)d_in[5];
    const float* b1     = (const float*)d_in[6];
    const float* W2     = (const float*)d_in[7];
    const float* att_s2 = (const float*)d_in[8];
    const float* att_d2 = (const float*)d_in[9];
    const float* b2     = (const float*)d_in[10];
    const float* fc1w   = (const float*)d_in[11];
    const float* fc1b   = (const float*)d_in[12];
    const float* fc2w   = (const float*)d_in[13];
    const float* fc2b   = (const float*)d_in[14];
    float* out = (float*)d_out;

    int N = in_sizes[0] / 256;      // 50000
    int E = in_sizes[1] / 2;        // 800000
    int ET = E + N;
    int ETpad = (ET + 63) & ~63;
    int NB = (N + 255) / 256;

    char* ws = (char*)d_ws;
    size_t off = 0;
    auto alloc = [&](size_t bytes) { size_t o = off; off = (off + bytes + 255) & ~255ULL; return o; };
    u16*  w1x    = (u16*)(ws + alloc(272 * 256 * 2));
    u16*  h1b    = (u16*)(ws + alloc((size_t)N * 256 * 2));
    float* asad  = (float*)(ws + alloc((size_t)N * 8 * 4));
    u16*  hin2b  = (u16*)(ws + alloc((size_t)N * 256 * 2));
    u16*  h2b    = (u16*)(ws + alloc((size_t)N * 32 * 2));
    float* as2   = (float*)(ws + alloc((size_t)N * 4));
    float* ad2   = (float*)(ws + alloc((size_t)N * 4));
    float* out2  = (float*)(ws + alloc((size_t)N * 32 * 4));
    int* cnt     = (int*)(ws + alloc((size_t)(N + 1) * 4));
    int* row_ptr = (int*)(ws + alloc((size_t)(N + 1) * 4));
    int* cursor  = (int*)(ws + alloc((size_t)(N + 1) * 4));
    int* col     = (int*)(ws + alloc((size_t)ET * 4));
    int* bsum    = (int*)(ws + alloc((size_t)NB * 4));
    int* bbase   = (int*)(ws + alloc((size_t)NB * 4));
    float* alphas1 = (float*)(ws + alloc((size_t)ETpad * 4 * 4));
    float* invl1   = (float*)(ws + alloc((size_t)N * 4 * 4));
    float* alphas2 = (float*)(ws + alloc((size_t)ET * 4));
    float* invl2   = (float*)(ws + alloc((size_t)N * 4));
    (void)ws_size; (void)n_in; (void)out_size;

    // prep (independent of CSR)
    prep_w1<<<256, 256, 0, stream>>>(W1, att_s1, att_d1, w1x);

    // CSR build
    zero_i32<<<(N + 1 + 255) / 256, 256, 0, stream>>>(cnt, N + 1);
    hist_kernel<<<(ET + 255) / 256, 256, 0, stream>>>(ei, E, N, cnt);
    bsum_kernel<<<NB, 256, 0, stream>>>(cnt, bsum, N);
    bscan_kernel<<<1, 256, 0, stream>>>(bsum, bbase, NB);
    local_scan_kernel<<<NB, 256, 0, stream>>>(cnt, bbase, row_ptr, cursor, N, ET);
    scatter_kernel<<<(ET + 255) / 256, 256, 0, stream>>>(ei, E, N, cursor, col);

    // conv1
    int nwaves = (N + 15) / 16;
    gemm1_direct<<<(nwaves + 3) / 4, 256, 0, stream>>>(x, w1x, h1b, asad, N);
    att_alpha1<<<(N * 64 + 255) / 256, 256, 0, stream>>>(asad, row_ptr, col, alphas1, invl1, N, ETpad);
    conv1_gather<<<(N * 64 + 255) / 256, 256, 0, stream>>>(h1b, alphas1, invl1, row_ptr, col, b1, hin2b, N, ETpad);

    // conv2
    gemm2_att<<<(N + 63) / 64, 256, 0, stream>>>(hin2b, W2, att_s2, att_d2, h2b, as2, ad2, N);
    att_alpha2<<<(N * 64 + 255) / 256, 256, 0, stream>>>(as2, ad2, row_ptr, col, alphas2, invl2, N);
    conv2_gather<<<(N * 32 + 255) / 256, 256, 0, stream>>>(h2b, alphas2, invl2, row_ptr, col, b2, out2, N);

    // pool + fc
    pool_fc<<<64, 256, 0, stream>>>(out2, batch, fc1w, fc1b, fc2w, fc2b, out, N);
}